// Round 1
// baseline (192.629 us; speedup 1.0000x reference)
//
#include <hip/hip_runtime.h>
#include <hip/hip_bf16.h>

// MaskedAttention R6: pipeline restructure of attn.
// - R5 issued all prefetch BEFORE __syncthreads; __syncthreads drains vmcnt(0)
//   -> full VMEM latency exposed at all 9 barriers. Now prefetch is issued
//   AFTER the barrier and consumed before the next one -> barrier drain free.
// - 3.48M bank conflicts == 8 shfl_down x 7cyc x 62208 wave-jts. Replaced with
//   direct conditional A-frag loads on kq==0 lanes.
// - V^T bf16 tiles (vt) produced once in feat (same RNE values) instead of
//   9x-redundant per-block convert (16 strided scalar loads + 8 pk2/wave-jt).
// - normalizer: n_i = q'_i . w,  w[b,h,m] = sum_j cmask[h,j]*k'[b,h,j,m]
//   (exact reassociation of the same fp32 products) -> cms + per-jt nacc gone.
// LDS 27648 B -> 5 blocks/CU.

#define B_ 16
#define L_ 576
#define H_ 12
#define D_ 64
#define M_ 8
#define NUM_STAB 1e-3f
#define RATIO 0.35355339059327373f  // 1/sqrt(M)

typedef __attribute__((ext_vector_type(8))) short short8;
typedef __attribute__((ext_vector_type(4))) float f32x4;

union Pack {
    uint4 u4;
    short8 s8;
    uint2 u2[2];
    unsigned u[4];
    unsigned short us[8];
};

__device__ inline unsigned short f2bf(float x) {  // RNE fp32 -> bf16 bits
    union { float f; unsigned u; } a; a.f = x;
    unsigned r = (a.u + 0x7FFFu + ((a.u >> 16) & 1u)) >> 16;
    return (unsigned short)r;
}
__device__ inline unsigned pk2(float lo, float hi) {  // v_cvt_pk_bf16_f32 (RNE)
    __hip_bfloat162 h = __float22bfloat162_rn(make_float2(lo, hi));
    union { __hip_bfloat162 b; unsigned u; } c; c.b = h;
    return c.u;
}
__device__ inline float bf2f(unsigned short u) {
    union { unsigned u; float f; } c; c.u = (unsigned)u << 16; return c.f;
}

// ws layout: cmask H*L f32 | w B*H*M f32 | qp bf16 | kp bf16 | vt bf16
#define WS_W_OFF  (H_ * L_)
#define WS_QP_OFF (H_ * L_ + B_ * H_ * M_)
#define QP_ELEMS  ((size_t)B_ * H_ * L_ * M_)

// ---------------- kernel 1: features (bf16) + cmask col-sums + V^T bf16 tiles ----------------
__global__ __launch_bounds__(256) void feat_kernel(const float* __restrict__ q,
                                                   const float* __restrict__ k,
                                                   const float* __restrict__ v,
                                                   const float* __restrict__ proj,
                                                   const float* __restrict__ mask,
                                                   unsigned short* __restrict__ qp,
                                                   unsigned short* __restrict__ kp,
                                                   float* __restrict__ cmask,
                                                   unsigned short* __restrict__ vt) {
    __shared__ float cred[4][16];
    const int lc = blockIdx.x, h = blockIdx.y, b = blockIdx.z, t = threadIdx.x;
    const int wv = t >> 6, l = t & 63, r8 = l >> 3, c8 = l & 7;
    const int row = lc * 32 + wv * 8 + r8;

    float4 pj0[8], pj1[8];
#pragma unroll
    for (int m = 0; m < 8; ++m) {
        pj0[m] = *(const float4*)(proj + m * 64 + c8 * 8);
        pj1[m] = *(const float4*)(proj + m * 64 + c8 * 8 + 4);
    }

#pragma unroll
    for (int s = 0; s < 2; ++s) {
        const float* src = s ? k : q;
        unsigned short* dst = s ? kp : qp;
        const float* xp = src + (((size_t)b * L_ + row) * H_ + h) * D_ + c8 * 8;
        float4 x0 = *(const float4*)xp;
        float4 x1 = *(const float4*)(xp + 4);
        x0.x *= RATIO; x0.y *= RATIO; x0.z *= RATIO; x0.w *= RATIO;
        x1.x *= RATIO; x1.y *= RATIO; x1.z *= RATIO; x1.w *= RATIO;
        float p[8];
#pragma unroll
        for (int m = 0; m < 8; ++m) {
            p[m] = x0.x * pj0[m].x + x0.y * pj0[m].y + x0.z * pj0[m].z + x0.w * pj0[m].w
                 + x1.x * pj1[m].x + x1.y * pj1[m].y + x1.z * pj1[m].z + x1.w * pj1[m].w;
        }
#pragma unroll
        for (int st = 1; st <= 4; st <<= 1) {
#pragma unroll
            for (int m = 0; m < 8; ++m) p[m] += __shfl_xor(p[m], st, 64);
        }
        float r = p[0];
        r = (c8 == 1) ? p[1] : r;
        r = (c8 == 2) ? p[2] : r;
        r = (c8 == 3) ? p[3] : r;
        r = (c8 == 4) ? p[4] : r;
        r = (c8 == 5) ? p[5] : r;
        r = (c8 == 6) ? p[6] : r;
        r = (c8 == 7) ? p[7] : r;
        r = fmaxf(r, 0.f) + NUM_STAB;
        dst[((size_t)(b * H_ + h) * L_ + row) * 8 + c8] = f2bf(r);
    }

    // ---- V^T bf16 tile fill: vt[((b*H+h)*9 + jt)*4096 + d*64 + jl], jl = j - 64*jt ----
    // thread owns (d = t>>2, 8-wide j-group). Block covers j in [lc*32, lc*32+32).
    {
        const int dv = t >> 2;
        const int jl = (lc & 1) * 32 + (t & 3) * 8;
        const int jt9 = lc >> 1;
        const float* vsrc = v + (((size_t)b * L_ + jt9 * 64 + jl) * H_ + h) * D_ + dv;
        float tv[8];
#pragma unroll
        for (int e = 0; e < 8; ++e) tv[e] = vsrc[(size_t)e * (H_ * D_)];
        Pack pv;
#pragma unroll
        for (int q4 = 0; q4 < 4; ++q4) pv.u[q4] = pk2(tv[2 * q4], tv[2 * q4 + 1]);
        *(uint4*)&vt[((size_t)(b * H_ + h) * 9 + jt9) * 4096 + dv * 64 + jl] = pv.u4;
    }

    if (b < 2) {
        const int c = t & 15, rg = t >> 4;
        const int col0 = lc * 32 + b * 16;
        const float* mb = mask + (size_t)h * L_ * L_ + col0 + c;
        float a = 0.f;
#pragma unroll 4
        for (int k2 = 0; k2 < 36; ++k2) a += mb[(size_t)(rg + 16 * k2) * L_];
        a += __shfl_xor(a, 16, 64);
        a += __shfl_xor(a, 32, 64);
        if ((l >> 4) == 0) cred[wv][c] = a;
        __syncthreads();
        if (t < 16) cmask[h * L_ + col0 + t] = cred[0][t] + cred[1][t] + cred[2][t] + cred[3][t];
    }
}

// ---------------- kernel 2: w[b,h,m] = sum_j cmask[h,j] * k'[b,h,j,m] ----------------
__global__ __launch_bounds__(64) void wsum_kernel(const unsigned short* __restrict__ kp,
                                                  const float* __restrict__ cmask,
                                                  float* __restrict__ wbuf) {
    const int bh = blockIdx.x, lx = threadIdx.x;
    const int h = bh % H_;
    const unsigned short* kpb = kp + (size_t)bh * L_ * 8;
    const float* cm = cmask + h * L_;
    float a[8] = {0.f, 0.f, 0.f, 0.f, 0.f, 0.f, 0.f, 0.f};
    for (int j = lx; j < L_; j += 64) {
        const float c = cm[j];
        Pack pk; pk.u4 = *(const uint4*)(kpb + (size_t)j * 8);
#pragma unroll
        for (int m = 0; m < 8; ++m) a[m] += c * bf2f(pk.us[m]);
    }
#pragma unroll
    for (int st = 1; st < 64; st <<= 1) {
#pragma unroll
        for (int m = 0; m < 8; ++m) a[m] += __shfl_xor(a[m], st, 64);
    }
    float r = a[0];
    r = (lx == 1) ? a[1] : r;
    r = (lx == 2) ? a[2] : r;
    r = (lx == 3) ? a[3] : r;
    r = (lx == 4) ? a[4] : r;
    r = (lx == 5) ? a[5] : r;
    r = (lx == 6) ? a[6] : r;
    r = (lx == 7) ? a[7] : r;
    if (lx < 8) wbuf[(size_t)bh * 8 + lx] = r;
}

// ---------------- kernel 3: main attention ----------------
// grid 1728 (XCD-swizzled), block 256 (4 waves). 64 i x 64 d per block; 9 j-tiles.
// Per jt: phaseA (4 MFMA, A-frags prefetched) -> Bt/Sp stores -> barrier
// (vmcnt already 0: all globals consumed pre-barrier) -> prefetch jt+1
// (overlaps phase B) -> phase B (8 MFMA).
__global__ __launch_bounds__(256, 5) void attn_kernel(const float* __restrict__ mask,
                                                      const unsigned short* __restrict__ qp,
                                                      const unsigned short* __restrict__ kp,
                                                      const unsigned short* __restrict__ vt,
                                                      const float* __restrict__ wbuf,
                                                      float* __restrict__ out) {
    __shared__ __align__(16) unsigned short Sp[4 * 16 * 72];  // 9216 B, wave-private chunks
    __shared__ __align__(16) unsigned short Bt[2][64 * 72];   // 18432 B, double-buffered

    const int t = threadIdx.x;
    int id = blockIdx.x;
    const int bhi = id & 7; id >>= 3;
    const int blo = id & 1; id >>= 1;
    const int it = id % 9, h = id / 9;
    const int b = bhi * 2 + blo;
    const int i0 = it * 64;

    const int wv = t >> 6, l = t & 63, c15 = l & 15, kq = l >> 4;
    const int bd = t >> 3, bg = t & 7;        // Bt staging: rows bd and bd+32, j-group bg
    const int vt_off = bd * 64 + bg * 8;      // shorts within an 8KB vt tile

    const float* maskbase = mask + (size_t)h * L_ * L_ + (size_t)(i0 + 16 * wv + c15) * L_;
    const unsigned short* kpb = kp + (size_t)(b * H_ + h) * L_ * 8;
    const unsigned short* vtb = vt + (size_t)(b * H_ + h) * 9 * 4096;
    unsigned short* SpW = Sp + wv * 16 * 72;

    // loop-invariant Q' B-fragment (kq==0 lanes hold Q'[i0+16wv+c15][m0..7])
    short8 Bq;
    {
        Pack pk; pk.u4 = make_uint4(0, 0, 0, 0);
        if (kq == 0)
            pk.u4 = *(const uint4*)(qp + ((size_t)(b * H_ + h) * L_ + i0 + 16 * wv + c15) * 8);
        Bq = pk.s8;
    }

    f32x4 acc0 = {0.f, 0.f, 0.f, 0.f}, acc1 = acc0, acc2 = acc0, acc3 = acc0;
    const f32x4 zz = {0.f, 0.f, 0.f, 0.f};

    // prologue prefetch for jt=0. Issue order = consumption order:
    // A-frags (phaseA), vt (Bt store), mask (Sp store).
    uint4 a0 = make_uint4(0, 0, 0, 0), a1 = a0, a2 = a0, a3 = a0;
    uint4 vt0, vt1;
    float4 mv0, mv1, mv2, mv3;
    if (kq == 0) {
        a0 = *(const uint4*)(kpb + (size_t)(c15) * 8);
        a1 = *(const uint4*)(kpb + (size_t)(16 + c15) * 8);
        a2 = *(const uint4*)(kpb + (size_t)(32 + c15) * 8);
        a3 = *(const uint4*)(kpb + (size_t)(48 + c15) * 8);
    }
    vt0 = *(const uint4*)(vtb + vt_off);
    vt1 = *(const uint4*)(vtb + 2048 + vt_off);
    mv0 = *(const float4*)(maskbase + 0 + 4 * kq);
    mv1 = *(const float4*)(maskbase + 16 + 4 * kq);
    mv2 = *(const float4*)(maskbase + 32 + 4 * kq);
    mv3 = *(const float4*)(maskbase + 48 + 4 * kq);

    for (int jt = 0; jt < 9; ++jt) {
        const int slab = jt & 1;

        // ---- phase A: S[j][i] for 64 j (A-frags direct-loaded, no shfl) ----
        f32x4 s0, s1, s2, s3;
        {
            Pack p0, p1, p2, p3;
            p0.u4 = a0; p1.u4 = a1; p2.u4 = a2; p3.u4 = a3;
            s0 = __builtin_amdgcn_mfma_f32_16x16x32_bf16(p0.s8, Bq, zz, 0, 0, 0);
            s1 = __builtin_amdgcn_mfma_f32_16x16x32_bf16(p1.s8, Bq, zz, 0, 0, 0);
            s2 = __builtin_amdgcn_mfma_f32_16x16x32_bf16(p2.s8, Bq, zz, 0, 0, 0);
            s3 = __builtin_amdgcn_mfma_f32_16x16x32_bf16(p3.s8, Bq, zz, 0, 0, 0);
        }

        // ---- Bt[slab] staging (prefetched vt regs; conflict-free b128 writes) ----
        *(uint4*)&Bt[slab][bd * 72 + bg * 8] = vt0;
        *(uint4*)&Bt[slab][(bd + 32) * 72 + bg * 8] = vt1;

        // ---- masked-S store (bf16) ----
        {
            uint2 st2;
            st2.x = pk2(s0[0] * mv0.x, s0[1] * mv0.y);
            st2.y = pk2(s0[2] * mv0.z, s0[3] * mv0.w);
            *(uint2*)&SpW[c15 * 72 + 0 + 4 * kq] = st2;
            st2.x = pk2(s1[0] * mv1.x, s1[1] * mv1.y);
            st2.y = pk2(s1[2] * mv1.z, s1[3] * mv1.w);
            *(uint2*)&SpW[c15 * 72 + 16 + 4 * kq] = st2;
            st2.x = pk2(s2[0] * mv2.x, s2[1] * mv2.y);
            st2.y = pk2(s2[2] * mv2.z, s2[3] * mv2.w);
            *(uint2*)&SpW[c15 * 72 + 32 + 4 * kq] = st2;
            st2.x = pk2(s3[0] * mv3.x, s3[1] * mv3.y);
            st2.y = pk2(s3[2] * mv3.z, s3[3] * mv3.w);
            *(uint2*)&SpW[c15 * 72 + 48 + 4 * kq] = st2;
        }

        __syncthreads();  // all globals already consumed -> vmcnt(0) drain is free

        // ---- prefetch jt+1 AFTER the barrier: overlaps phase B ----
        {
            const int jn = (jt < 8) ? jt + 1 : 0;
            const int j0n = jn * 64;
            if (kq == 0) {
                a0 = *(const uint4*)(kpb + (size_t)(j0n + c15) * 8);
                a1 = *(const uint4*)(kpb + (size_t)(j0n + 16 + c15) * 8);
                a2 = *(const uint4*)(kpb + (size_t)(j0n + 32 + c15) * 8);
                a3 = *(const uint4*)(kpb + (size_t)(j0n + 48 + c15) * 8);
            }
            vt0 = *(const uint4*)(vtb + (size_t)jn * 4096 + vt_off);
            vt1 = *(const uint4*)(vtb + (size_t)jn * 4096 + 2048 + vt_off);
            mv0 = *(const float4*)(maskbase + j0n + 0 + 4 * kq);
            mv1 = *(const float4*)(maskbase + j0n + 16 + 4 * kq);
            mv2 = *(const float4*)(maskbase + j0n + 32 + 4 * kq);
            mv3 = *(const float4*)(maskbase + j0n + 48 + 4 * kq);
        }

        // ---- phase B: O += S.V over K=64 ----
        {
            short8 As0 = *(const short8*)&SpW[c15 * 72 + kq * 8];
            short8 As1 = *(const short8*)&SpW[c15 * 72 + 32 + kq * 8];
            const unsigned short* bp0 = &Bt[slab][c15 * 72 + kq * 8];
            const unsigned short* bp1 = bp0 + 16 * 72;
            const unsigned short* bp2 = bp0 + 32 * 72;
            const unsigned short* bp3 = bp0 + 48 * 72;
            acc0 = __builtin_amdgcn_mfma_f32_16x16x32_bf16(As0, *(const short8*)bp0, acc0, 0, 0, 0);
            acc0 = __builtin_amdgcn_mfma_f32_16x16x32_bf16(As1, *(const short8*)(bp0 + 32), acc0, 0, 0, 0);
            acc1 = __builtin_amdgcn_mfma_f32_16x16x32_bf16(As0, *(const short8*)bp1, acc1, 0, 0, 0);
            acc1 = __builtin_amdgcn_mfma_f32_16x16x32_bf16(As1, *(const short8*)(bp1 + 32), acc1, 0, 0, 0);
            acc2 = __builtin_amdgcn_mfma_f32_16x16x32_bf16(As0, *(const short8*)bp2, acc2, 0, 0, 0);
            acc2 = __builtin_amdgcn_mfma_f32_16x16x32_bf16(As1, *(const short8*)(bp2 + 32), acc2, 0, 0, 0);
            acc3 = __builtin_amdgcn_mfma_f32_16x16x32_bf16(As0, *(const short8*)bp3, acc3, 0, 0, 0);
            acc3 = __builtin_amdgcn_mfma_f32_16x16x32_bf16(As1, *(const short8*)(bp3 + 32), acc3, 0, 0, 0);
        }
    }

    // ---- epilogue: normalizer n_i = q'_i . w  (exact reassociation of old sum) ----
    const float* wp = wbuf + (size_t)(b * H_ + h) * 8;
    const float4 w0 = *(const float4*)wp;
    const float4 w1 = *(const float4*)(wp + 4);
    Pack pq;
    pq.u4 = *(const uint4*)(qp + ((size_t)(b * H_ + h) * L_ + i0 + 16 * wv + c15) * 8);
    float n = bf2f(pq.us[0]) * w0.x + bf2f(pq.us[1]) * w0.y +
              bf2f(pq.us[2]) * w0.z + bf2f(pq.us[3]) * w0.w +
              bf2f(pq.us[4]) * w1.x + bf2f(pq.us[5]) * w1.y +
              bf2f(pq.us[6]) * w1.z + bf2f(pq.us[7]) * w1.w;
    float iv[4];
#pragma unroll
    for (int r = 0; r < 4; ++r) iv[r] = 1.0f / __shfl(n, 4 * kq + r, 64);

    float* ob = out + (((size_t)b * L_ + i0 + 16 * wv + 4 * kq) * H_ + h) * D_ + c15;
    const f32x4 aa[4] = {acc0, acc1, acc2, acc3};
#pragma unroll
    for (int di = 0; di < 4; ++di)
#pragma unroll
        for (int r = 0; r < 4; ++r)
            ob[(size_t)r * (H_ * D_) + 16 * di] = aa[di][r] * iv[r];
}

extern "C" void kernel_launch(void* const* d_in, const int* in_sizes, int n_in,
                              void* d_out, int out_size, void* d_ws, size_t ws_size,
                              hipStream_t stream) {
    const float* q    = (const float*)d_in[0];
    const float* k    = (const float*)d_in[1];
    const float* v    = (const float*)d_in[2];
    const float* proj = (const float*)d_in[3];
    const float* mask = (const float*)d_in[4];
    float* out = (float*)d_out;

    float* ws = (float*)d_ws;
    float* cmask = ws;
    float* wbuf  = ws + WS_W_OFF;
    unsigned short* qp_w = (unsigned short*)(ws + WS_QP_OFF);
    unsigned short* kp_w = qp_w + QP_ELEMS;
    unsigned short* vt_w = kp_w + QP_ELEMS;   // B*H*L*D bf16 = 14.2 MB (ws total ~17.8 MB)

    feat_kernel<<<dim3(L_ / 32, H_, B_), 256, 0, stream>>>(q, k, v, proj, mask, qp_w, kp_w, cmask, vt_w);
    wsum_kernel<<<B_ * H_, 64, 0, stream>>>(kp_w, cmask, wbuf);
    attn_kernel<<<1728, 256, 0, stream>>>(mask, qp_w, kp_w, vt_w, wbuf, out);
}